// Round 11
// baseline (55.997 us; speedup 1.0000x reference)
//
#include <hip/hip_runtime.h>
#include <cstddef>
#include <cstdint>

// KPNextBlock: M=N=50000, H=32, C=128, K=15, GROUPS=8, CPG=16 -> K*CPG=240,
// RADIUS=1.2, SIGMA=0.9.
namespace {
constexpr int H_N    = 32;
constexpr int C_F    = 128;
constexpr int K_P    = 15;
constexpr int MODC   = 240;
constexpr int ROWS_B = 64;    // rows per GEMM block
}

typedef __attribute__((ext_vector_type(8))) short short8v;
typedef __attribute__((ext_vector_type(4))) float f32x4;

__device__ __forceinline__ unsigned short bf16_hi(float f) {
    unsigned u = __builtin_bit_cast(unsigned, f);
    unsigned r = (u + 0x7FFFu + ((u >> 16) & 1u)) >> 16;
    return (unsigned short)r;
}
__device__ __forceinline__ float bf16_f(unsigned short h) {
    unsigned u = ((unsigned)h) << 16;
    return __builtin_bit_cast(float, u);
}

// ---------------------------------------------------------------------------
// Pre-pass: w1 [128][128] and w2 [128][240] -> bf16, TRANSPOSED to [col][k]
// so MFMA B-fragments are 16B-contiguous per lane.
// ---------------------------------------------------------------------------
__global__ __launch_bounds__(256)
void split_w_kernel(const float* __restrict__ w1, const float* __restrict__ w2,
                    unsigned short* __restrict__ w1t, unsigned short* __restrict__ w2t)
{
    const int i = blockIdx.x * 256 + threadIdx.x;
    if (i < C_F * C_F) {
        const int c = i >> 7, j = i & 127;          // w1[c][j]
        w1t[j * C_F + c] = bf16_hi(w1[i]);
    }
    const int i2 = i - C_F * C_F;
    if (i2 >= 0 && i2 < C_F * MODC) {
        const int c = i2 / MODC, j = i2 - c * MODC; // w2[c][j]
        w2t[j * C_F + c] = bf16_hi(w2[i2]);
    }
}

// ---------------------------------------------------------------------------
// GEMM 1: h = leaky_relu(x @ w1 + b1) -> bf16 [rows][128].
// 64-row blocks, 8 waves; wave owns one 16-col tile. ONE barrier total.
// B-fragments from global (w1t is 32KB, L2-hot: every block reads the same).
// ---------------------------------------------------------------------------
__global__ __launch_bounds__(512, 2)
void p1_kernel(const float* __restrict__ s_feats,
               const unsigned short* __restrict__ w1t,
               const float* __restrict__ b1,
               unsigned short* __restrict__ hg,     // bf16 [rows][128]
               int m_base, int rows_total)
{
    __shared__ __align__(16) unsigned char lds[16384];   // x tile, swizzled

    const int t  = threadIdx.x;
    const int r0 = blockIdx.x * ROWS_B;
    const int rows = min(rows_total - r0, ROWS_B);

    // stage x: fp32 -> bf16, swizzled LDS [row][k]
    {
        const int row = t >> 3;          // 0..63
        const int k0  = (t & 7) << 4;    // 0,16,...,112
        const float4* src = reinterpret_cast<const float4*>(
            s_feats + (size_t)(m_base + r0 + row) * C_F + k0);
        #pragma unroll
        for (int s = 0; s < 2; ++s) {
            float v[8];
            if (row < rows) {
                const float4 a = src[s * 2 + 0];
                const float4 b = src[s * 2 + 1];
                v[0] = a.x; v[1] = a.y; v[2] = a.z; v[3] = a.w;
                v[4] = b.x; v[5] = b.y; v[6] = b.z; v[7] = b.w;
            } else {
                #pragma unroll
                for (int e = 0; e < 8; ++e) v[e] = 0.f;
            }
            short8v hv;
            #pragma unroll
            for (int e = 0; e < 8; ++e) hv[e] = (short)bf16_hi(v[e]);
            const unsigned addr = (unsigned)((row * 256 + (k0 + s * 8) * 2) ^ ((row & 7) << 4));
            *reinterpret_cast<short8v*>(lds + addr) = hv;
        }
    }
    __syncthreads();

    const int wave = t >> 6, lane = t & 63;
    const int wc = wave;           // col tile 0..7
    const int g  = lane >> 4;      // k-block
    const int ln = lane & 15;
    const int col = wc * 16 + ln;

    f32x4 acc[4];
    {
        const float b = b1[col];
        #pragma unroll
        for (int rt = 0; rt < 4; ++rt) acc[rt] = f32x4{b, b, b, b};
    }
    #pragma unroll
    for (int ks = 0; ks < 4; ++ks) {
        short8v a[4];
        #pragma unroll
        for (int rt = 0; rt < 4; ++rt) {
            const int row = rt * 16 + ln;
            const unsigned addr = (unsigned)((row * 256 + (ks * 32 + g * 8) * 2) ^ ((row & 7) << 4));
            a[rt] = *reinterpret_cast<const short8v*>(lds + addr);
        }
        const short8v b = *reinterpret_cast<const short8v*>(w1t + (size_t)col * C_F + ks * 32 + g * 8);
        #pragma unroll
        for (int rt = 0; rt < 4; ++rt)
            acc[rt] = __builtin_amdgcn_mfma_f32_16x16x32_bf16(a[rt], b, acc[rt], 0, 0, 0);
    }

    // leaky_relu + bf16 store (C/D: col=ln-based, row=g*4+r)
    #pragma unroll
    for (int rt = 0; rt < 4; ++rt) {
        #pragma unroll
        for (int r = 0; r < 4; ++r) {
            float v = acc[rt][r];
            v = v > 0.f ? v : 0.1f * v;
            const int row = rt * 16 + g * 4 + r;
            if (row < rows)
                hg[(size_t)(r0 + row) * C_F + col] = bf16_hi(v);
        }
    }
}

// ---------------------------------------------------------------------------
// GEMM 2: mod = sigmoid(h @ w2) -> bf16 [rows][240].
// 64-row blocks, 8 waves; wave owns col-tiles {w, w+8}. ONE barrier total.
// ---------------------------------------------------------------------------
__global__ __launch_bounds__(512, 2)
void p2_kernel(const unsigned short* __restrict__ hg,
               const unsigned short* __restrict__ w2t,
               unsigned short* __restrict__ modg,   // bf16 [rows][240]
               int rows_total)
{
    __shared__ __align__(16) unsigned char lds[16384];   // h tile, swizzled

    const int t  = threadIdx.x;
    const int r0 = blockIdx.x * ROWS_B;
    const int rows = min(rows_total - r0, ROWS_B);

    // stage h: bf16 copy, swizzled LDS [row][k]
    {
        const int row = t >> 3;          // 0..63
        const int k0  = (t & 7) << 4;    // 0,16,...,112
        #pragma unroll
        for (int s = 0; s < 2; ++s) {
            short8v hv;
            if (row < rows) {
                hv = *reinterpret_cast<const short8v*>(
                    hg + (size_t)(r0 + row) * C_F + k0 + s * 8);
            } else {
                #pragma unroll
                for (int e = 0; e < 8; ++e) hv[e] = 0;
            }
            const unsigned addr = (unsigned)((row * 256 + (k0 + s * 8) * 2) ^ ((row & 7) << 4));
            *reinterpret_cast<short8v*>(lds + addr) = hv;
        }
    }
    __syncthreads();

    const int wave = t >> 6, lane = t & 63;
    const int wc = wave;           // base col tile 0..7
    const int g  = lane >> 4;      // k-block
    const int ln = lane & 15;

    f32x4 acc[4][2];
    #pragma unroll
    for (int rt = 0; rt < 4; ++rt)
        #pragma unroll
        for (int cs = 0; cs < 2; ++cs) acc[rt][cs] = f32x4{0.f, 0.f, 0.f, 0.f};

    #pragma unroll
    for (int ks = 0; ks < 4; ++ks) {
        short8v a[4];
        #pragma unroll
        for (int rt = 0; rt < 4; ++rt) {
            const int row = rt * 16 + ln;
            const unsigned addr = (unsigned)((row * 256 + (ks * 32 + g * 8) * 2) ^ ((row & 7) << 4));
            a[rt] = *reinterpret_cast<const short8v*>(lds + addr);
        }
        #pragma unroll
        for (int cs = 0; cs < 2; ++cs) {
            const int ctile = wc + 8 * cs;          // wave-uniform guard, static acc idx
            if (ctile < K_P) {
                const int col = ctile * 16 + ln;
                const short8v b = *reinterpret_cast<const short8v*>(
                    w2t + (size_t)col * C_F + ks * 32 + g * 8);
                #pragma unroll
                for (int rt = 0; rt < 4; ++rt)
                    acc[rt][cs] = __builtin_amdgcn_mfma_f32_16x16x32_bf16(a[rt], b, acc[rt][cs], 0, 0, 0);
            }
        }
    }

    // sigmoid + bf16 store
    #pragma unroll
    for (int rt = 0; rt < 4; ++rt) {
        #pragma unroll
        for (int cs = 0; cs < 2; ++cs) {
            const int ctile = wc + 8 * cs;
            if (ctile < K_P) {
                const int col = ctile * 16 + ln;
                #pragma unroll
                for (int r = 0; r < 4; ++r) {
                    const int row = rt * 16 + g * 4 + r;
                    if (row < rows) {
                        const float v = 1.f / (1.f + __expf(-acc[rt][cs][r]));
                        modg[(size_t)(r0 + row) * MODC + col] = bf16_hi(v);
                    }
                }
            }
        }
    }
}

// ---------------------------------------------------------------------------
// Kernel 3: geometry + sparse gather/accumulate. One wave (64 lanes) per query
// (round-2-verified structure: 12500 blocks -> latency hidden by TLP).
// ---------------------------------------------------------------------------
__global__ __launch_bounds__(256)
void kpconv_kernel(const float* __restrict__ q_pts,
                   const float* __restrict__ s_pts,
                   const float* __restrict__ s_feats,
                   const int* __restrict__ nbi,
                   const float* __restrict__ da_scale,
                   const float* __restrict__ weights,
                   const float* __restrict__ kp,
                   const unsigned short* __restrict__ mod,  // chunk-local bf16 [rows, 240]
                   float* __restrict__ out,
                   int m_base, int rows_total)
{
    const int t    = threadIdx.x;
    const int lane = t & 63;
    const int r    = blockIdx.x * 4 + (t >> 6);
    if (r >= rows_total) return;
    const int m = m_base + r;

    const float qx = q_pts[m * 3 + 0];
    const float qy = q_pts[m * 3 + 1];
    const float qz = q_pts[m * 3 + 2];
    const float das = da_scale[m];

    int   idx = 0, nn = 0;
    float fl  = 0.f;
    if (lane < H_N) {
        idx = nbi[(size_t)m * H_N + lane];
        const float sx = s_pts[idx * 3 + 0];
        const float sy = s_pts[idx * 3 + 1];
        const float sz = s_pts[idx * 3 + 2];
        // plain fp32 (no fma contraction) to match numpy rounding at argmin ties
        const float dx = __fsub_rn(sx, qx);
        const float dy = __fsub_rn(sy, qy);
        const float dz = __fsub_rn(sz, qz);
        const float dd = __fadd_rn(__fadd_rn(__fmul_rn(dx, dx), __fmul_rn(dy, dy)),
                                   __fmul_rn(dz, dz));
        // |kp| < 1.2 strictly => |d| >= 0.9 + 1.2*da implies infl == 0 exactly.
        const float reach = 0.9f + 1.2f * das;
        if (dd < reach * reach) {
            float best = 3.4e38f; int bi = 0;
            #pragma unroll
            for (int k = 0; k < K_P; ++k) {
                const float ex = __fsub_rn(dx, __fmul_rn(kp[k * 3 + 0], das));
                const float ey = __fsub_rn(dy, __fmul_rn(kp[k * 3 + 1], das));
                const float ez = __fsub_rn(dz, __fmul_rn(kp[k * 3 + 2], das));
                const float d2 = __fadd_rn(__fadd_rn(__fmul_rn(ex, ex), __fmul_rn(ey, ey)),
                                           __fmul_rn(ez, ez));
                if (d2 < best) { best = d2; bi = k; }
            }
            const float f = 1.f - sqrtf(best) / 0.9f;
            fl = fmaxf(f, 0.f);
            nn = bi;
        }
    }

    unsigned long long mask = __ballot(fl > 0.f);
    const int c0 = lane << 1;
    float2 acc = {0.f, 0.f};
    while (mask) {
        const int h = __builtin_ctzll(mask);
        mask &= mask - 1;
        const int   ih = __shfl(idx, h);
        const int   nh = __shfl(nn, h);
        const float fh = __shfl(fl, h);
        const float2 fv = *reinterpret_cast<const float2*>(s_feats + (size_t)ih * C_F + c0);
        const float2 wv = *reinterpret_cast<const float2*>(weights + nh * C_F + c0);
        const float  mv = bf16_f(mod[(size_t)r * MODC + nh * 16 + (lane >> 2)]);
        const float  s  = fh * mv;
        acc.x = fmaf(fv.x * wv.x, s, acc.x);
        acc.y = fmaf(fv.y * wv.y, s, acc.y);
    }
    reinterpret_cast<float2*>(out + (size_t)m * C_F)[lane] = acc;
}

// ---------------------------------------------------------------------------
extern "C" void kernel_launch(void* const* d_in, const int* in_sizes, int n_in,
                              void* d_out, int out_size, void* d_ws, size_t ws_size,
                              hipStream_t stream)
{
    const float* q_pts  = (const float*)d_in[0];
    const float* s_pts  = (const float*)d_in[1];
    const float* s_feat = (const float*)d_in[2];
    const int*   nbi    = (const int*)d_in[3];
    const float* da     = (const float*)d_in[4];
    const float* wts    = (const float*)d_in[5];
    const float* w1     = (const float*)d_in[6];
    const float* b1     = (const float*)d_in[7];
    const float* w2     = (const float*)d_in[8];
    const float* kp     = (const float*)d_in[9];
    float* out = (float*)d_out;

    const int M = in_sizes[4];   // da_scale has M elements

    // workspace: w1t 32KB | w2t 60KB | h bf16 [chunk][128] | mod bf16 [chunk][240]
    unsigned short* w1t = (unsigned short*)d_ws;
    unsigned short* w2t = w1t + C_F * C_F;
    size_t woff = ((size_t)(C_F * C_F + C_F * MODC) * sizeof(unsigned short) + 255) & ~(size_t)255;

    const int nsplit = (C_F * C_F + C_F * MODC + 255) / 256;
    split_w_kernel<<<dim3(nsplit), 256, 0, stream>>>(w1, w2, w1t, w2t);

    // per-row workspace: h 256B + mod 480B = 736B
    size_t cap = (ws_size - woff) / (size_t)((C_F + MODC) * sizeof(unsigned short));
    int chunk = (cap >= (size_t)M) ? M : (int)(cap & ~(size_t)63);
    if (chunk < 64) chunk = 64;

    unsigned short* hbuf = (unsigned short*)((char*)d_ws + woff);
    unsigned short* mod  = hbuf + (size_t)chunk * C_F;

    for (int m0 = 0; m0 < M; m0 += chunk) {
        int rows = M - m0; if (rows > chunk) rows = chunk;
        const int nb = (rows + ROWS_B - 1) / ROWS_B;
        p1_kernel<<<dim3(nb), 512, 0, stream>>>(s_feat, w1t, b1, hbuf, m0, rows);
        p2_kernel<<<dim3(nb), 512, 0, stream>>>(hbuf, w2t, mod, rows);
        kpconv_kernel<<<dim3((rows + 3) / 4), 256, 0, stream>>>(
            q_pts, s_pts, s_feat, nbi, da, wts, kp, mod, out, m0, rows);
    }
}

// Round 12
// 46.830 us; speedup vs baseline: 1.1958x; 1.1958x over previous
//
#include <hip/hip_runtime.h>
#include <cstddef>
#include <cstdint>

// KPNextBlock: M=N=50000, H=32, C=128, K=15, GROUPS=8, CPG=16 -> K*CPG=240,
// RADIUS=1.2, SIGMA=0.9.
namespace {
constexpr int H_N    = 32;
constexpr int C_F    = 128;
constexpr int K_P    = 15;
constexpr int MODC   = 240;
constexpr int ROWS_B = 64;     // rows (queries) per block
// LDS: x/h tile (swizzled bf16) 16KB | mod tile (linear bf16 [64][240]) 30KB
constexpr int X_OFF   = 0;
constexpr int MOD_OFF = 16384;
constexpr int LDS_SZ  = 16384 + ROWS_B * MODC * 2;   // 47104 B -> 3 blocks/CU
}

typedef __attribute__((ext_vector_type(8))) short short8v;
typedef __attribute__((ext_vector_type(4))) float f32x4;

__device__ __forceinline__ unsigned short bf16_hi(float f) {
    unsigned u = __builtin_bit_cast(unsigned, f);
    unsigned r = (u + 0x7FFFu + ((u >> 16) & 1u)) >> 16;
    return (unsigned short)r;
}
__device__ __forceinline__ float bf16_f(unsigned short h) {
    unsigned u = ((unsigned)h) << 16;
    return __builtin_bit_cast(float, u);
}

// ---------------------------------------------------------------------------
// Pre-pass: w1 [128][128] and w2 [128][240] -> bf16, TRANSPOSED to [col][k]
// so MFMA B-fragments are 16B-contiguous per lane.
// ---------------------------------------------------------------------------
__global__ __launch_bounds__(256)
void split_w_kernel(const float* __restrict__ w1, const float* __restrict__ w2,
                    unsigned short* __restrict__ w1t, unsigned short* __restrict__ w2t)
{
    const int i = blockIdx.x * 256 + threadIdx.x;
    if (i < C_F * C_F) {
        const int c = i >> 7, j = i & 127;          // w1[c][j]
        w1t[j * C_F + c] = bf16_hi(w1[i]);
    }
    const int i2 = i - C_F * C_F;
    if (i2 >= 0 && i2 < C_F * MODC) {
        const int c = i2 / MODC, j = i2 - c * MODC; // w2[c][j]
        w2t[j * C_F + c] = bf16_hi(w2[i2]);
    }
}

// ---------------------------------------------------------------------------
// Fused kernel: per 64-row block (8 waves, 512 threads):
//   stage x (bf16, swizzled LDS) -> GEMM1 (wave owns col-tile w; h -> LDS) ->
//   GEMM2 (tiles {w, w+8}; sigmoid; mod -> LDS, NEVER global) ->
//   kpconv for the same 64 queries (8 per wave), out -> global.
// Weights stream from L2 (every block reads the same 92KB of bf16 w1t/w2t).
// 2 dispatches total per call; no global intermediates (round-11 had 4
// dispatches + 73MB of h/mod round-trips).
// ---------------------------------------------------------------------------
__global__ __launch_bounds__(512, 2)
void fused_kernel(const float* __restrict__ q_pts,
                  const float* __restrict__ s_pts,
                  const float* __restrict__ s_feats,
                  const int* __restrict__ nbi,
                  const float* __restrict__ da_scale,
                  const float* __restrict__ weights,
                  const float* __restrict__ kp,
                  const unsigned short* __restrict__ w1t,
                  const unsigned short* __restrict__ w2t,
                  const float* __restrict__ b1,
                  float* __restrict__ out,
                  int M)
{
    __shared__ __align__(16) unsigned char lds[LDS_SZ];

    const int t  = threadIdx.x;
    const int r0 = blockIdx.x * ROWS_B;
    const int rows = min(M - r0, ROWS_B);

    // ---- stage x: fp32 -> bf16, swizzled LDS [row][k] ----
    {
        const int row = t >> 3;          // 0..63
        const int k0  = (t & 7) << 4;    // 0,16,...,112
        const float4* src = reinterpret_cast<const float4*>(
            s_feats + (size_t)(r0 + row) * C_F + k0);
        #pragma unroll
        for (int s = 0; s < 2; ++s) {
            float v[8];
            if (row < rows) {
                const float4 a = src[s * 2 + 0];
                const float4 b = src[s * 2 + 1];
                v[0] = a.x; v[1] = a.y; v[2] = a.z; v[3] = a.w;
                v[4] = b.x; v[5] = b.y; v[6] = b.z; v[7] = b.w;
            } else {
                #pragma unroll
                for (int e = 0; e < 8; ++e) v[e] = 0.f;
            }
            short8v hv;
            #pragma unroll
            for (int e = 0; e < 8; ++e) hv[e] = (short)bf16_hi(v[e]);
            const unsigned addr = (unsigned)((row * 256 + (k0 + s * 8) * 2) ^ ((row & 7) << 4));
            *reinterpret_cast<short8v*>(lds + X_OFF + addr) = hv;
        }
    }
    __syncthreads();

    const int wave = t >> 6, lane = t & 63;
    const int wc = wave;           // col tile 0..7
    const int g  = lane >> 4;      // k-block
    const int ln = lane & 15;

    // ---- GEMM1: h = leaky_relu(x @ w1 + b1); wave owns col-tile wc ----
    {
        const int col = wc * 16 + ln;
        f32x4 acc[4];
        {
            const float b = b1[col];
            #pragma unroll
            for (int rt = 0; rt < 4; ++rt) acc[rt] = f32x4{b, b, b, b};
        }
        #pragma unroll
        for (int ks = 0; ks < 4; ++ks) {
            short8v a[4];
            #pragma unroll
            for (int rt = 0; rt < 4; ++rt) {
                const int row = rt * 16 + ln;
                const unsigned addr = (unsigned)((row * 256 + (ks * 32 + g * 8) * 2) ^ ((row & 7) << 4));
                a[rt] = *reinterpret_cast<const short8v*>(lds + X_OFF + addr);
            }
            const short8v b = *reinterpret_cast<const short8v*>(
                w1t + (size_t)col * C_F + ks * 32 + g * 8);
            #pragma unroll
            for (int rt = 0; rt < 4; ++rt)
                acc[rt] = __builtin_amdgcn_mfma_f32_16x16x32_bf16(a[rt], b, acc[rt], 0, 0, 0);
        }
        __syncthreads();   // all waves done reading x before h overwrites it

        // leaky_relu + writeback (C/D: col=ln, row=g*4+r)
        #pragma unroll
        for (int rt = 0; rt < 4; ++rt) {
            #pragma unroll
            for (int r = 0; r < 4; ++r) {
                float v = acc[rt][r];
                v = v > 0.f ? v : 0.1f * v;
                const int row = rt * 16 + g * 4 + r;
                const unsigned addr = (unsigned)((row * 256 + col * 2) ^ ((row & 7) << 4));
                *reinterpret_cast<unsigned short*>(lds + X_OFF + addr) = bf16_hi(v);
            }
        }
    }
    __syncthreads();

    // ---- GEMM2: mod = sigmoid(h @ w2) -> LDS tile; wave owns {wc, wc+8} ----
    {
        f32x4 acc2[4][2];
        #pragma unroll
        for (int rt = 0; rt < 4; ++rt)
            #pragma unroll
            for (int cs = 0; cs < 2; ++cs) acc2[rt][cs] = f32x4{0.f, 0.f, 0.f, 0.f};

        #pragma unroll
        for (int ks = 0; ks < 4; ++ks) {
            short8v a[4];
            #pragma unroll
            for (int rt = 0; rt < 4; ++rt) {
                const int row = rt * 16 + ln;
                const unsigned addr = (unsigned)((row * 256 + (ks * 32 + g * 8) * 2) ^ ((row & 7) << 4));
                a[rt] = *reinterpret_cast<const short8v*>(lds + X_OFF + addr);
            }
            #pragma unroll
            for (int cs = 0; cs < 2; ++cs) {
                const int ctile = wc + 8 * cs;      // wave-uniform guard, static acc idx
                if (ctile < K_P) {
                    const int col = ctile * 16 + ln;
                    const short8v b = *reinterpret_cast<const short8v*>(
                        w2t + (size_t)col * C_F + ks * 32 + g * 8);
                    #pragma unroll
                    for (int rt = 0; rt < 4; ++rt)
                        acc2[rt][cs] = __builtin_amdgcn_mfma_f32_16x16x32_bf16(a[rt], b, acc2[rt][cs], 0, 0, 0);
                }
            }
        }

        // sigmoid -> mod LDS (linear [64][240] bf16)
        #pragma unroll
        for (int rt = 0; rt < 4; ++rt) {
            #pragma unroll
            for (int cs = 0; cs < 2; ++cs) {
                const int ctile = wc + 8 * cs;
                if (ctile < K_P) {
                    const int col = ctile * 16 + ln;
                    #pragma unroll
                    for (int r = 0; r < 4; ++r) {
                        const int row = rt * 16 + g * 4 + r;
                        const float v = 1.f / (1.f + __expf(-acc2[rt][cs][r]));
                        *reinterpret_cast<unsigned short*>(
                            lds + MOD_OFF + row * (MODC * 2) + col * 2) = bf16_hi(v);
                    }
                }
            }
        }
    }
    __syncthreads();

    // ---- kpconv: 8 queries per wave, mod from LDS ----
    for (int i = 0; i < 8; ++i) {
        const int ql = i * 8 + wave;           // 0..63
        if (ql >= rows) continue;
        const int mq = r0 + ql;

        const float qx = q_pts[mq * 3 + 0];
        const float qy = q_pts[mq * 3 + 1];
        const float qz = q_pts[mq * 3 + 2];
        const float das = da_scale[mq];

        int   idx = 0, nn = 0;
        float fl  = 0.f;
        if (lane < H_N) {
            idx = nbi[(size_t)mq * H_N + lane];
            const float sx = s_pts[idx * 3 + 0];
            const float sy = s_pts[idx * 3 + 1];
            const float sz = s_pts[idx * 3 + 2];
            // plain fp32 (no fma contraction) to match numpy rounding at argmin ties
            const float dx = __fsub_rn(sx, qx);
            const float dy = __fsub_rn(sy, qy);
            const float dz = __fsub_rn(sz, qz);
            const float dd = __fadd_rn(__fadd_rn(__fmul_rn(dx, dx), __fmul_rn(dy, dy)),
                                       __fmul_rn(dz, dz));
            // |kp| < 1.2 strictly => |d| >= 0.9 + 1.2*da implies infl == 0 exactly.
            const float reach = 0.9f + 1.2f * das;
            if (dd < reach * reach) {
                float best = 3.4e38f; int bi = 0;
                #pragma unroll
                for (int k = 0; k < K_P; ++k) {
                    const float ex = __fsub_rn(dx, __fmul_rn(kp[k * 3 + 0], das));
                    const float ey = __fsub_rn(dy, __fmul_rn(kp[k * 3 + 1], das));
                    const float ez = __fsub_rn(dz, __fmul_rn(kp[k * 3 + 2], das));
                    const float d2 = __fadd_rn(__fadd_rn(__fmul_rn(ex, ex), __fmul_rn(ey, ey)),
                                               __fmul_rn(ez, ez));
                    if (d2 < best) { best = d2; bi = k; }
                }
                const float f = 1.f - sqrtf(best) / 0.9f;
                fl = fmaxf(f, 0.f);
                nn = bi;
            }
        }

        unsigned long long mask = __ballot(fl > 0.f);
        const int c0 = lane << 1;
        float2 acc = {0.f, 0.f};
        while (mask) {
            const int hb = __builtin_ctzll(mask);
            mask &= mask - 1;
            const int   ih = __shfl(idx, hb);
            const int   nh = __shfl(nn, hb);
            const float fh = __shfl(fl, hb);
            const float2 fv = *reinterpret_cast<const float2*>(s_feats + (size_t)ih * C_F + c0);
            const float2 wv = *reinterpret_cast<const float2*>(weights + nh * C_F + c0);
            const float  mv = bf16_f(*reinterpret_cast<const unsigned short*>(
                lds + MOD_OFF + ql * (MODC * 2) + (nh * 16 + (lane >> 2)) * 2));
            const float  s  = fh * mv;
            acc.x = fmaf(fv.x * wv.x, s, acc.x);
            acc.y = fmaf(fv.y * wv.y, s, acc.y);
        }
        reinterpret_cast<float2*>(out + (size_t)mq * C_F)[lane] = acc;
    }
}

// ---------------------------------------------------------------------------
extern "C" void kernel_launch(void* const* d_in, const int* in_sizes, int n_in,
                              void* d_out, int out_size, void* d_ws, size_t ws_size,
                              hipStream_t stream)
{
    const float* q_pts  = (const float*)d_in[0];
    const float* s_pts  = (const float*)d_in[1];
    const float* s_feat = (const float*)d_in[2];
    const int*   nbi    = (const int*)d_in[3];
    const float* da     = (const float*)d_in[4];
    const float* wts    = (const float*)d_in[5];
    const float* w1     = (const float*)d_in[6];
    const float* b1     = (const float*)d_in[7];
    const float* w2     = (const float*)d_in[8];
    const float* kp     = (const float*)d_in[9];
    float* out = (float*)d_out;

    const int M = in_sizes[4];   // da_scale has M elements

    // workspace: only the transposed bf16 weights (92KB)
    unsigned short* w1t = (unsigned short*)d_ws;
    unsigned short* w2t = w1t + C_F * C_F;

    const int nsplit = (C_F * C_F + C_F * MODC + 255) / 256;
    split_w_kernel<<<dim3(nsplit), 256, 0, stream>>>(w1, w2, w1t, w2t);

    const int nb = (M + ROWS_B - 1) / ROWS_B;
    fused_kernel<<<dim3(nb), 512, 0, stream>>>(
        q_pts, s_pts, s_feat, nbi, da, wts, kp, w1t, w2t, b1, out, M);
}

// Round 13
// 42.826 us; speedup vs baseline: 1.3075x; 1.0935x over previous
//
#include <hip/hip_runtime.h>
#include <cstddef>
#include <cstdint>

// KPNextBlock: M=N=50000, H=32, C=128, K=15, GROUPS=8, CPG=16 -> K*CPG=240,
// RADIUS=1.2, SIGMA=0.9.
namespace {
constexpr int H_N    = 32;
constexpr int C_F    = 128;
constexpr int K_P    = 15;
constexpr int MODC   = 240;
constexpr int ROWS_B = 64;     // rows (queries) per block
// LDS: x/h swizzled tile occupies [0,16384); mod (linear bf16 [64][240]) is
// written over the SAME region (plus 14KB more) after GEMM2's h reads are
// all in registers -- one extra barrier makes the lifetimes disjoint.
// 30720 B -> 5 blocks/CU by LDS -> capped at 32 waves/CU (FULL occupancy;
// round-12's 47KB allowed only 24).
constexpr int LDS_SZ  = ROWS_B * MODC * 2;   // 30720
}

typedef __attribute__((ext_vector_type(8))) short short8v;
typedef __attribute__((ext_vector_type(4))) float f32x4;

__device__ __forceinline__ unsigned short bf16_hi(float f) {
    unsigned u = __builtin_bit_cast(unsigned, f);
    unsigned r = (u + 0x7FFFu + ((u >> 16) & 1u)) >> 16;
    return (unsigned short)r;
}
__device__ __forceinline__ float bf16_f(unsigned short h) {
    unsigned u = ((unsigned)h) << 16;
    return __builtin_bit_cast(float, u);
}

// ---------------------------------------------------------------------------
// Pre-pass: w1 [128][128] and w2 [128][240] -> bf16, TRANSPOSED to [col][k]
// so MFMA B-fragments are 16B-contiguous per lane.
// ---------------------------------------------------------------------------
__global__ __launch_bounds__(256)
void split_w_kernel(const float* __restrict__ w1, const float* __restrict__ w2,
                    unsigned short* __restrict__ w1t, unsigned short* __restrict__ w2t)
{
    const int i = blockIdx.x * 256 + threadIdx.x;
    if (i < C_F * C_F) {
        const int c = i >> 7, j = i & 127;          // w1[c][j]
        w1t[j * C_F + c] = bf16_hi(w1[i]);
    }
    const int i2 = i - C_F * C_F;
    if (i2 >= 0 && i2 < C_F * MODC) {
        const int c = i2 / MODC, j = i2 - c * MODC; // w2[c][j]
        w2t[j * C_F + c] = bf16_hi(w2[i2]);
    }
}

// ---------------------------------------------------------------------------
// Fused kernel, per 64-row block (8 waves, 512 threads):
//   stage x (bf16, swizzled LDS) -> GEMM1 (h -> LDS) -> GEMM2 (sigmoid in
//   regs) -> mod -> LDS (overlapping x/h region) -> kpconv (2 queries per
//   wave-pass, half-wave each; 4 passes), out -> global.
// launch_bounds(512,4): VGPR cap 64 (round-12 used 40) -> 8 waves/SIMD OK.
// ---------------------------------------------------------------------------
__global__ __launch_bounds__(512, 4)
void fused_kernel(const float* __restrict__ q_pts,
                  const float* __restrict__ s_pts,
                  const float* __restrict__ s_feats,
                  const int* __restrict__ nbi,
                  const float* __restrict__ da_scale,
                  const float* __restrict__ weights,
                  const float* __restrict__ kp,
                  const unsigned short* __restrict__ w1t,
                  const unsigned short* __restrict__ w2t,
                  const float* __restrict__ b1,
                  float* __restrict__ out,
                  int M)
{
    __shared__ __align__(16) unsigned char lds[LDS_SZ];

    const int t  = threadIdx.x;
    const int r0 = blockIdx.x * ROWS_B;
    const int rows = min(M - r0, ROWS_B);

    // ---- stage x: fp32 -> bf16, swizzled LDS [row][k] (bytes [0,16384)) ----
    {
        const int row = t >> 3;          // 0..63
        const int k0  = (t & 7) << 4;    // 0,16,...,112
        const float4* src = reinterpret_cast<const float4*>(
            s_feats + (size_t)(r0 + row) * C_F + k0);
        #pragma unroll
        for (int s = 0; s < 2; ++s) {
            float v[8];
            if (row < rows) {
                const float4 a = src[s * 2 + 0];
                const float4 b = src[s * 2 + 1];
                v[0] = a.x; v[1] = a.y; v[2] = a.z; v[3] = a.w;
                v[4] = b.x; v[5] = b.y; v[6] = b.z; v[7] = b.w;
            } else {
                #pragma unroll
                for (int e = 0; e < 8; ++e) v[e] = 0.f;
            }
            short8v hv;
            #pragma unroll
            for (int e = 0; e < 8; ++e) hv[e] = (short)bf16_hi(v[e]);
            const unsigned addr = (unsigned)((row * 256 + (k0 + s * 8) * 2) ^ ((row & 7) << 4));
            *reinterpret_cast<short8v*>(lds + addr) = hv;
        }
    }
    __syncthreads();

    const int wave = t >> 6, lane = t & 63;
    const int wc = wave;           // col tile 0..7
    const int g  = lane >> 4;      // k-block
    const int ln = lane & 15;

    // ---- GEMM1: h = leaky_relu(x @ w1 + b1); wave owns col-tile wc ----
    {
        const int col = wc * 16 + ln;
        f32x4 acc[4];
        {
            const float b = b1[col];
            #pragma unroll
            for (int rt = 0; rt < 4; ++rt) acc[rt] = f32x4{b, b, b, b};
        }
        #pragma unroll
        for (int ks = 0; ks < 4; ++ks) {
            short8v a[4];
            #pragma unroll
            for (int rt = 0; rt < 4; ++rt) {
                const int row = rt * 16 + ln;
                const unsigned addr = (unsigned)((row * 256 + (ks * 32 + g * 8) * 2) ^ ((row & 7) << 4));
                a[rt] = *reinterpret_cast<const short8v*>(lds + addr);
            }
            const short8v b = *reinterpret_cast<const short8v*>(
                w1t + (size_t)col * C_F + ks * 32 + g * 8);
            #pragma unroll
            for (int rt = 0; rt < 4; ++rt)
                acc[rt] = __builtin_amdgcn_mfma_f32_16x16x32_bf16(a[rt], b, acc[rt], 0, 0, 0);
        }
        __syncthreads();   // all waves done reading x before h overwrites it

        // leaky_relu + writeback (C/D: col=ln, row=g*4+r)
        #pragma unroll
        for (int rt = 0; rt < 4; ++rt) {
            #pragma unroll
            for (int r = 0; r < 4; ++r) {
                float v = acc[rt][r];
                v = v > 0.f ? v : 0.1f * v;
                const int row = rt * 16 + g * 4 + r;
                const unsigned addr = (unsigned)((row * 256 + col * 2) ^ ((row & 7) << 4));
                *reinterpret_cast<unsigned short*>(lds + addr) = bf16_hi(v);
            }
        }
    }
    __syncthreads();

    // ---- GEMM2: mod = sigmoid(h @ w2) into REGISTERS; wave owns {wc,wc+8} ----
    f32x4 acc2[4][2];
    #pragma unroll
    for (int rt = 0; rt < 4; ++rt)
        #pragma unroll
        for (int cs = 0; cs < 2; ++cs) acc2[rt][cs] = f32x4{0.f, 0.f, 0.f, 0.f};

    #pragma unroll
    for (int ks = 0; ks < 4; ++ks) {
        short8v a[4];
        #pragma unroll
        for (int rt = 0; rt < 4; ++rt) {
            const int row = rt * 16 + ln;
            const unsigned addr = (unsigned)((row * 256 + (ks * 32 + g * 8) * 2) ^ ((row & 7) << 4));
            a[rt] = *reinterpret_cast<const short8v*>(lds + addr);
        }
        #pragma unroll
        for (int cs = 0; cs < 2; ++cs) {
            const int ctile = wc + 8 * cs;      // wave-uniform guard, static acc idx
            if (ctile < K_P) {
                const int col = ctile * 16 + ln;
                const short8v b = *reinterpret_cast<const short8v*>(
                    w2t + (size_t)col * C_F + ks * 32 + g * 8);
                #pragma unroll
                for (int rt = 0; rt < 4; ++rt)
                    acc2[rt][cs] = __builtin_amdgcn_mfma_f32_16x16x32_bf16(a[rt], b, acc2[rt][cs], 0, 0, 0);
            }
        }
    }
    // sigmoid in registers
    #pragma unroll
    for (int rt = 0; rt < 4; ++rt)
        #pragma unroll
        for (int cs = 0; cs < 2; ++cs)
            #pragma unroll
            for (int r = 0; r < 4; ++r)
                acc2[rt][cs][r] = 1.f / (1.f + __expf(-acc2[rt][cs][r]));

    __syncthreads();   // h reads complete -> mod may overwrite the region

    // ---- mod -> LDS (linear bf16 [64][240], bytes [0, 30720)) ----
    #pragma unroll
    for (int rt = 0; rt < 4; ++rt) {
        #pragma unroll
        for (int cs = 0; cs < 2; ++cs) {
            const int ctile = wc + 8 * cs;
            if (ctile < K_P) {
                const int col = ctile * 16 + ln;
                #pragma unroll
                for (int r = 0; r < 4; ++r) {
                    const int row = rt * 16 + g * 4 + r;
                    *reinterpret_cast<unsigned short*>(
                        lds + row * (MODC * 2) + col * 2) = bf16_hi(acc2[rt][cs][r]);
                }
            }
        }
    }
    __syncthreads();

    // ---- kpconv: 2 queries per pass (one per half-wave), 4 passes ----
    const int hl   = lane & 31;      // neighbor index / channel-group lane
    const int half = lane >> 5;
    const int c0   = hl << 2;        // 4 channels per lane
    for (int i = 0; i < 4; ++i) {
        const int ql = i * 16 + wave * 2 + half;
        const bool valid = ql < rows;
        const int mq = r0 + ql;

        int   idx = 0, nn = 0;
        float fl  = 0.f;
        if (valid) {
            const float qx = q_pts[mq * 3 + 0];
            const float qy = q_pts[mq * 3 + 1];
            const float qz = q_pts[mq * 3 + 2];
            const float das = da_scale[mq];
            idx = nbi[(size_t)mq * H_N + hl];
            const float sx = s_pts[idx * 3 + 0];
            const float sy = s_pts[idx * 3 + 1];
            const float sz = s_pts[idx * 3 + 2];
            // plain fp32 (no fma contraction) to match numpy rounding at argmin ties
            const float dx = __fsub_rn(sx, qx);
            const float dy = __fsub_rn(sy, qy);
            const float dz = __fsub_rn(sz, qz);
            const float dd = __fadd_rn(__fadd_rn(__fmul_rn(dx, dx), __fmul_rn(dy, dy)),
                                       __fmul_rn(dz, dz));
            // |kp| < 1.2 strictly => |d| >= 0.9 + 1.2*da implies infl == 0 exactly.
            const float reach = 0.9f + 1.2f * das;
            if (dd < reach * reach) {
                float best = 3.4e38f; int bi = 0;
                #pragma unroll
                for (int k = 0; k < K_P; ++k) {
                    const float ex = __fsub_rn(dx, __fmul_rn(kp[k * 3 + 0], das));
                    const float ey = __fsub_rn(dy, __fmul_rn(kp[k * 3 + 1], das));
                    const float ez = __fsub_rn(dz, __fmul_rn(kp[k * 3 + 2], das));
                    const float d2 = __fadd_rn(__fadd_rn(__fmul_rn(ex, ex), __fmul_rn(ey, ey)),
                                               __fmul_rn(ez, ez));
                    if (d2 < best) { best = d2; bi = k; }
                }
                const float f = 1.f - sqrtf(best) / 0.9f;
                fl = fmaxf(f, 0.f);
                nn = bi;
            }
        }

        const unsigned long long mask = __ballot(fl > 0.f);
        unsigned long long mymask = half ? (mask & 0xFFFFFFFF00000000ull)
                                         : (mask & 0x00000000FFFFFFFFull);
        float4 acc = {0.f, 0.f, 0.f, 0.f};
        while (mymask) {
            const int hb = __builtin_ctzll(mymask);   // absolute lane (correct half)
            mymask &= mymask - 1;
            const int   ih = __shfl(idx, hb);
            const int   nh = __shfl(nn, hb);
            const float fh = __shfl(fl, hb);
            const float4 fv = *reinterpret_cast<const float4*>(s_feats + (size_t)ih * C_F + c0);
            const float4 wv = *reinterpret_cast<const float4*>(weights + nh * C_F + c0);
            const float  mv = bf16_f(*reinterpret_cast<const unsigned short*>(
                lds + ql * (MODC * 2) + (nh * 16 + (hl >> 1)) * 2));
            const float  s  = fh * mv;
            acc.x = fmaf(fv.x * wv.x, s, acc.x);
            acc.y = fmaf(fv.y * wv.y, s, acc.y);
            acc.z = fmaf(fv.z * wv.z, s, acc.z);
            acc.w = fmaf(fv.w * wv.w, s, acc.w);
        }
        if (valid)
            *reinterpret_cast<float4*>(out + (size_t)mq * C_F + c0) = acc;
    }
}

// ---------------------------------------------------------------------------
extern "C" void kernel_launch(void* const* d_in, const int* in_sizes, int n_in,
                              void* d_out, int out_size, void* d_ws, size_t ws_size,
                              hipStream_t stream)
{
    const float* q_pts  = (const float*)d_in[0];
    const float* s_pts  = (const float*)d_in[1];
    const float* s_feat = (const float*)d_in[2];
    const int*   nbi    = (const int*)d_in[3];
    const float* da     = (const float*)d_in[4];
    const float* wts    = (const float*)d_in[5];
    const float* w1     = (const float*)d_in[6];
    const float* b1     = (const float*)d_in[7];
    const float* w2     = (const float*)d_in[8];
    const float* kp     = (const float*)d_in[9];
    float* out = (float*)d_out;

    const int M = in_sizes[4];   // da_scale has M elements

    // workspace: only the transposed bf16 weights (92KB)
    unsigned short* w1t = (unsigned short*)d_ws;
    unsigned short* w2t = w1t + C_F * C_F;

    const int nsplit = (C_F * C_F + C_F * MODC + 255) / 256;
    split_w_kernel<<<dim3(nsplit), 256, 0, stream>>>(w1, w2, w1t, w2t);

    const int nb = (M + ROWS_B - 1) / ROWS_B;
    fused_kernel<<<dim3(nb), 512, 0, stream>>>(
        q_pts, s_pts, s_feat, nbi, da, wts, kp, w1t, w2t, b1, out, M);
}